// Round 8
// baseline (292.746 us; speedup 1.0000x reference)
//
#include <hip/hip_runtime.h>
#include <math.h>

// GCN-VGAE encoder, N=100000 nodes, E=1600000 edges, F=H=128, O=64 (fp32 in/out).
// Strategy:
//   - CSR build: two-level ATOMIC-FREE radix partition (global atomics on gfx950
//     write through at 32B/op; plain stores are L2-absorbed). Coarse partition
//     by col>>8 with LDS cursors, then per-bucket fine CSR build in LDS.
//     deg/dinv folded into build_fine via native ds_add_f32 (+lgkmcnt drain —
//     inline-asm DS ops are invisible to compiler waitcnt tracking).
//     build_fine also emits a DEGREE-BALANCED node permutation (per-bucket LDS
//     counting sort by edge count): aggregate waves pair nodes of near-equal
//     degree, removing the max-of-2-Poisson wave-imbalance (~14%).
//   - Aggregation: warp-gather, 8 nodes x 32 lanes per block, bf16 rows,
//     BATCH-4 edges in flight (batch-8 raised VGPR 24->36, occupancy 70->60%,
//     regressed — occupancy beats per-wave batching on this fabric-bound pass).
//     FETCH 194MB = compulsory 8-XCD re-fetch of the 25.6MB bf16 table.
//     (LDS-tile SpMM experiment rounds 2-4: 20x slower, reverted.)
//   - agg2 epilogue emits PRESPLIT hi/lo bf16 planes (VALU hidden under fabric
//     stalls); gemm2's A-staging becomes a pure copy — no fp32 split VALU.
//   - Feature matrices bf16 (halves gather traffic). Symmetric norm factored:
//     pre-scale rows by dinv, aggregate RAW weights, post-scale by dinv[c].
//   - GEMMs on MFMA (16x16x32 bf16) with SPLIT precision: A=Ahi+Alo, W=Whi+Wlo,
//     C = Ahi*Whi + Alo*Whi + Ahi*Wlo  (error ~2^-18, fp32-grade).
//   - conv2/conv3 fused: agg2 = A_norm @ h once, then one GEMM with [Wmu|Wls].

#define NBLK 512    // coarse-partition blocks; each handles ceil(E/NBLK) edges

typedef __attribute__((ext_vector_type(8))) short bf16x8;
typedef __attribute__((ext_vector_type(4))) float f32x4;

__device__ __forceinline__ unsigned short f2bf_rne(float f) {
  unsigned int u = __float_as_uint(f);
  u += 0x7FFFu + ((u >> 16) & 1u);
  return (unsigned short)(u >> 16);
}

__device__ __forceinline__ float bf2f(unsigned short h) {
  return __uint_as_float(((unsigned int)h) << 16);
}

__device__ __forceinline__ unsigned int pack2(unsigned short a, unsigned short b) {
  return (unsigned int)a | ((unsigned int)b << 16);
}

// Native fire-and-forget LDS float atomic add (ds byte address = low 32b of
// the generic pointer).
__device__ __forceinline__ void lds_fadd(float* addr, float v) {
  unsigned int off = (unsigned int)(size_t)addr;
  asm volatile("ds_add_f32 %0, %1" : : "v"(off), "v"(v) : "memory");
}

// Drain ALL outstanding DS ops (incl. inline-asm ones the compiler can't see).
// MUST precede any __syncthreads() that follows lds_fadd use.
__device__ __forceinline__ void ds_drain() {
  asm volatile("s_waitcnt lgkmcnt(0)" ::: "memory");
}

// ---------------- CSR build: two-level atomic-free partition ----------------

// Per-block LDS histogram over coarse buckets (col>>8). G[bucket][blk] layout.
__global__ __launch_bounds__(256) void hist_coarse(const int* __restrict__ col,
                                                   int* __restrict__ G,
                                                   int E, int nbuck, int epb) {
  __shared__ int h[512];
  int blk = blockIdx.x;
  for (int i = threadIdx.x; i < nbuck; i += 256) h[i] = 0;
  __syncthreads();
  int beg = blk * epb;
  int end = min(beg + epb, E);
  for (int p = beg + threadIdx.x; p < end; p += 256)
    atomicAdd(&h[col[p] >> 8], 1);
  __syncthreads();
  for (int i = threadIdx.x; i < nbuck; i += 256)
    G[(size_t)i * NBLK + blk] = h[i];
}

// Per-bucket exclusive scan over the NBLK block-counts; emits bucket totals.
__global__ __launch_bounds__(NBLK) void scan_bucket(int* __restrict__ G,
                                                    int* __restrict__ tot) {
  __shared__ int s[NBLK];
  int b = blockIdx.x;
  int v = G[(size_t)b * NBLK + threadIdx.x];
  s[threadIdx.x] = v;
  __syncthreads();
  for (int off = 1; off < NBLK; off <<= 1) {
    int t = (threadIdx.x >= off) ? s[threadIdx.x - off] : 0;
    __syncthreads();
    s[threadIdx.x] += t;
    __syncthreads();
  }
  G[(size_t)b * NBLK + threadIdx.x] = s[threadIdx.x] - v;   // exclusive
  if (threadIdx.x == NBLK - 1) tot[b] = s[NBLK - 1];
}

// Exclusive scan of bucket totals -> start[0..nbuck] (start[nbuck]=E).
__global__ __launch_bounds__(512) void scan_start(const int* __restrict__ tot,
                                                  int* __restrict__ start,
                                                  int* __restrict__ row_ptr,
                                                  int nbuck, int N, int E) {
  __shared__ int s[512];
  int v = (threadIdx.x < nbuck) ? tot[threadIdx.x] : 0;
  s[threadIdx.x] = v;
  __syncthreads();
  for (int off = 1; off < 512; off <<= 1) {
    int t = (threadIdx.x >= off) ? s[threadIdx.x - off] : 0;
    __syncthreads();
    s[threadIdx.x] += t;
    __syncthreads();
  }
  if (threadIdx.x < nbuck) start[threadIdx.x] = s[threadIdx.x] - v;
  if (threadIdx.x == 511) start[nbuck] = E;
  if (threadIdx.x == 0) row_ptr[N] = E;
}

// Coarse scatter: LDS cursors (start[b] + G[b][blk]); packs row|colLow into .x.
// All writes are plain stores (L2 write-back) — zero global atomics.
__global__ __launch_bounds__(256) void partition_edges(
    const int* __restrict__ row, const int* __restrict__ col,
    const float* __restrict__ w, const int* __restrict__ G,
    const int* __restrict__ start, int2* __restrict__ part,
    int E, int nbuck, int epb) {
  __shared__ int cur[512];
  int blk = blockIdx.x;
  for (int i = threadIdx.x; i < nbuck; i += 256)
    cur[i] = start[i] + G[(size_t)i * NBLK + blk];
  __syncthreads();
  int beg = blk * epb;
  int end = min(beg + epb, E);
  for (int p = beg + threadIdx.x; p < end; p += 256) {
    int c = col[p];
    int pos = atomicAdd(&cur[c >> 8], 1);             // LDS atomic (int, native)
    part[pos] = make_int2(row[p] | ((c & 255) << 17), // row < 2^17
                          __float_as_int(w[p]));
  }
}

// Fine build: one block per bucket (256 nodes). LDS hist + scan -> row_ptr and
// exact CSR slots; accumulates deg (raw weight sum) -> dinv; and emits the
// degree-balanced permutation (per-bucket counting sort by edge count; invalid
// tail nodes key 255 so valid nodes exactly fill perm[0..N)).
__global__ __launch_bounds__(256) void build_fine(const int* __restrict__ start,
                                                  const int2* __restrict__ part,
                                                  int* __restrict__ row_ptr,
                                                  int2* __restrict__ csr,
                                                  float* __restrict__ dinv,
                                                  int* __restrict__ perm,
                                                  int N) {
  __shared__ int hist[256];
  __shared__ int sc[256];
  __shared__ int cur[256];
  __shared__ float deg[256];
  int b = blockIdx.x;
  int ebeg = start[b], eend = start[b + 1];
  hist[threadIdx.x] = 0;
  deg[threadIdx.x] = 0.f;
  __syncthreads();
  for (int p = ebeg + threadIdx.x; p < eend; p += 256) {
    int2 e = part[p];
    int dl = (e.x >> 17) & 255;
    atomicAdd(&hist[dl], 1);
    lds_fadd(&deg[dl], __int_as_float(e.y));
  }
  ds_drain();          // asm ds_add_f32 invisible to compiler waitcnt tracking
  __syncthreads();
  int v = hist[threadIdx.x];
  sc[threadIdx.x] = v;
  __syncthreads();
  for (int off = 1; off < 256; off <<= 1) {
    int t = (threadIdx.x >= off) ? sc[threadIdx.x - off] : 0;
    __syncthreads();
    sc[threadIdx.x] += t;
    __syncthreads();
  }
  int ex = sc[threadIdx.x] - v;   // exclusive
  int node = b * 256 + threadIdx.x;
  if (node < N) {
    row_ptr[node] = ebeg + ex;
    dinv[node] = 1.0f / sqrtf(1.0f + deg[threadIdx.x]);
  }
  cur[threadIdx.x] = ebeg + ex;
  __syncthreads();
  for (int p = ebeg + threadIdx.x; p < eend; p += 256) {
    int2 r = part[p];
    int pos = atomicAdd(&cur[(r.x >> 17) & 255], 1);       // LDS atomic (int)
    csr[pos] = make_int2(r.x & 0x1FFFF, r.y);
  }
  // ---- degree-balanced permutation: counting sort by edge count ----
  __syncthreads();                 // cur/sc/hist reusable now
  int key = (node < N) ? (v > 254 ? 254 : v) : 255;
  sc[threadIdx.x] = 0;
  __syncthreads();
  atomicAdd(&sc[key], 1);          // degree histogram
  __syncthreads();
  int dv = sc[threadIdx.x];
  hist[threadIdx.x] = dv;          // scan buffer
  __syncthreads();
  for (int off = 1; off < 256; off <<= 1) {
    int t = (threadIdx.x >= off) ? hist[threadIdx.x - off] : 0;
    __syncthreads();
    hist[threadIdx.x] += t;
    __syncthreads();
  }
  cur[threadIdx.x] = hist[threadIdx.x] - dv;   // exclusive degree-scan
  __syncthreads();
  int rank = atomicAdd(&cur[key], 1);
  if (node < N) perm[(b << 8) + rank] = node;
}

// Transpose + bf16-split both weight matrices in ONE launch:
//   i < 16384: W1 (128x128)     -> w1t_hi/lo[n][k]
//   else:      [Wmu|Wls] concat -> wct_hi/lo[n][k], + bias concat.
__global__ __launch_bounds__(256) void prep_weights(
    const float* __restrict__ W1,
    const float* __restrict__ Wmu, const float* __restrict__ Wls,
    const float* __restrict__ bmu, const float* __restrict__ bls,
    unsigned short* __restrict__ w1t_hi, unsigned short* __restrict__ w1t_lo,
    unsigned short* __restrict__ wct_hi, unsigned short* __restrict__ wct_lo,
    float* __restrict__ bcat) {
  int i = blockIdx.x * 256 + threadIdx.x;   // 0..32767
  if (i < 16384) {
    int n = i & 127, k = i >> 7;
    float f = W1[(size_t)k * 128 + n];
    unsigned short h = f2bf_rne(f);
    unsigned short l = f2bf_rne(f - bf2f(h));
    w1t_hi[(size_t)n * 128 + k] = h;
    w1t_lo[(size_t)n * 128 + k] = l;
  } else {
    int j = i - 16384;
    int n = j & 127, k = j >> 7;
    float f = (n < 64) ? Wmu[(size_t)k * 64 + n] : Wls[(size_t)k * 64 + (n - 64)];
    unsigned short h = f2bf_rne(f);
    unsigned short l = f2bf_rne(f - bf2f(h));
    wct_hi[(size_t)n * 128 + k] = h;
    wct_lo[(size_t)n * 128 + k] = l;
    if (j < 128) bcat[j] = (j < 64) ? bmu[j] : bls[j - 64];
  }
}

// C[M,128] = (A[M,128] @ W[128,128]) * rowscale[row] + bias, via split-bf16 MFMA.
// A path: either fp32 (split in-kernel) or PRESPLIT bf16 planes AHi/ALo
// (pure-copy staging, no VALU split). WtHi/WtLo are bf16, TRANSPOSED [n][k].
// Block: 256 thr = 4 waves, C-tile 128x128, wave computes 64x64 (4x4 of 16x16).
// LDS XOR-swizzle: slot ^ (row&7).
// Output: fp32 split (C0 cols<split, C1 rest) and/or bf16 mirror Cbf (stride 128).
__global__ __launch_bounds__(256) void gemm_mfma(
    const float* __restrict__ A,
    const unsigned short* __restrict__ AHi, const unsigned short* __restrict__ ALo,
    const unsigned short* __restrict__ WtHi, const unsigned short* __restrict__ WtLo,
    const float* __restrict__ bias, const float* __restrict__ rowscale,
    float* __restrict__ C0, float* __restrict__ C1,
    unsigned short* __restrict__ Cbf, int split, int M) {
  __shared__ uint4 sAhi[1024];   // [row 0..127][slot 0..7] 16B slots, swizzled
  __shared__ uint4 sAlo[1024];
  __shared__ uint4 sWhi[1024];   // [col 0..127][slot 0..7]
  __shared__ uint4 sWlo[1024];

  int tid = threadIdx.x;
  int lane = tid & 63, wid = tid >> 6;
  int wave_r = (wid >> 1) * 64, wave_c = (wid & 1) * 64;
  int lrow = lane & 15, lkb = lane >> 4;   // lkb = k-chunk 0..3
  int rowBase = blockIdx.x * 128;

  f32x4 acc[4][4];
#pragma unroll
  for (int mr = 0; mr < 4; ++mr)
#pragma unroll
    for (int nc = 0; nc < 4; ++nc) acc[mr][nc] = (f32x4){0.f, 0.f, 0.f, 0.f};

  const uint4* WtHi4 = (const uint4*)WtHi;   // row = 16 uint4 (128 bf16)
  const uint4* WtLo4 = (const uint4*)WtLo;
  const uint4* AHi4 = (const uint4*)AHi;
  const uint4* ALo4 = (const uint4*)ALo;

  for (int kt = 0; kt < 128; kt += 64) {
    __syncthreads();
    // stage W tile: 128 cols x 64 k (bf16, already split) -> swizzled LDS
#pragma unroll
    for (int j = 0; j < 4; ++j) {
      int g = tid + 256 * j;            // 0..1023
      int c = g >> 3, k8 = g & 7;
      int slot = k8 ^ (c & 7);
      sWhi[c * 8 + slot] = WtHi4[c * 16 + (kt >> 3) + k8];
      sWlo[c * 8 + slot] = WtLo4[c * 16 + (kt >> 3) + k8];
    }
    // stage A tile: 128 rows x 64 k -> swizzled LDS
    if (AHi) {
      // presplit path: pure copy
#pragma unroll
      for (int j = 0; j < 4; ++j) {
        int g = tid + 256 * j;
        int r = g >> 3, k8 = g & 7;
        int grow = rowBase + r;
        uint4 vh = make_uint4(0u, 0u, 0u, 0u);
        uint4 vl = vh;
        if (grow < M) {
          vh = AHi4[(size_t)grow * 16 + (kt >> 3) + k8];
          vl = ALo4[(size_t)grow * 16 + (kt >> 3) + k8];
        }
        int slot = k8 ^ (r & 7);
        sAhi[r * 8 + slot] = vh;
        sAlo[r * 8 + slot] = vl;
      }
    } else {
      // fp32 path: split hi/lo in-kernel
#pragma unroll
      for (int j = 0; j < 4; ++j) {
        int g = tid + 256 * j;          // 0..1023
        int r = g >> 3, k8 = g & 7;
        int grow = rowBase + r;
        float4 v0 = make_float4(0.f, 0.f, 0.f, 0.f);
        float4 v1 = v0;
        if (grow < M) {
          const float4* Ar = (const float4*)(A + (size_t)grow * 128 + kt);
          v0 = Ar[k8 * 2];
          v1 = Ar[k8 * 2 + 1];
        }
        float f[8] = {v0.x, v0.y, v0.z, v0.w, v1.x, v1.y, v1.z, v1.w};
        unsigned short h[8], l[8];
#pragma unroll
        for (int q = 0; q < 8; ++q) {
          h[q] = f2bf_rne(f[q]);
          l[q] = f2bf_rne(f[q] - bf2f(h[q]));
        }
        int slot = k8 ^ (r & 7);
        sAhi[r * 8 + slot] = make_uint4(pack2(h[0], h[1]), pack2(h[2], h[3]),
                                        pack2(h[4], h[5]), pack2(h[6], h[7]));
        sAlo[r * 8 + slot] = make_uint4(pack2(l[0], l[1]), pack2(l[2], l[3]),
                                        pack2(l[4], l[5]), pack2(l[6], l[7]));
      }
    }
    __syncthreads();
    // compute: 2 MFMA k-steps (K=32 each) per LDS tile
#pragma unroll
    for (int ks = 0; ks < 2; ++ks) {
      bf16x8 ah[4], al[4], bh[4], bl[4];
#pragma unroll
      for (int mr = 0; mr < 4; ++mr) {
        int r = wave_r + mr * 16 + lrow;
        int slot = (ks * 4 + lkb) ^ (r & 7);
        ah[mr] = *(const bf16x8*)&sAhi[r * 8 + slot];
        al[mr] = *(const bf16x8*)&sAlo[r * 8 + slot];
      }
#pragma unroll
      for (int nc = 0; nc < 4; ++nc) {
        int c = wave_c + nc * 16 + lrow;
        int slot = (ks * 4 + lkb) ^ (c & 7);
        bh[nc] = *(const bf16x8*)&sWhi[c * 8 + slot];
        bl[nc] = *(const bf16x8*)&sWlo[c * 8 + slot];
      }
#pragma unroll
      for (int mr = 0; mr < 4; ++mr)
#pragma unroll
        for (int nc = 0; nc < 4; ++nc) {
          acc[mr][nc] = __builtin_amdgcn_mfma_f32_16x16x32_bf16(
              ah[mr], bh[nc], acc[mr][nc], 0, 0, 0);
          acc[mr][nc] = __builtin_amdgcn_mfma_f32_16x16x32_bf16(
              al[mr], bh[nc], acc[mr][nc], 0, 0, 0);
          acc[mr][nc] = __builtin_amdgcn_mfma_f32_16x16x32_bf16(
              ah[mr], bl[nc], acc[mr][nc], 0, 0, 0);
        }
    }
  }

  // epilogue: D[row=(lane>>4)*4+reg][col=lane&15] per 16x16 tile
#pragma unroll
  for (int mr = 0; mr < 4; ++mr) {
    int Rb = rowBase + wave_r + mr * 16 + lkb * 4;
    float sc[4];
#pragma unroll
    for (int reg = 0; reg < 4; ++reg)
      sc[reg] = (rowscale && (Rb + reg) < M) ? rowscale[Rb + reg] : 1.0f;
#pragma unroll
    for (int nc = 0; nc < 4; ++nc) {
      int c = wave_c + nc * 16 + lrow;
      float bb = bias ? bias[c] : 0.f;
      f32x4 v = acc[mr][nc];
#pragma unroll
      for (int reg = 0; reg < 4; ++reg) {
        int R = Rb + reg;
        if (R >= M) continue;
        float val = v[reg] * sc[reg] + bb;
        if (Cbf) Cbf[(size_t)R * 128 + c] = f2bf_rne(val);
        if (C0) {
          if (c < split) C0[(size_t)R * split + c] = val;
          else           C1[(size_t)R * split + (c - split)] = val;
        }
      }
    }
  }
}

// 256 threads = 8 nodes x 32 lanes; each lane owns 4 channels (ushort4 = 8B bf16).
// Batch-4 edges in flight (proven optimum: 24 VGPR, ~70% occupancy).
// Nodes taken through the degree-balanced permutation: the 2 nodes sharing a
// 64-lane wave have near-equal degree -> no max-of-2 imbalance.
// Output: bf16 mirror (hout_bf) and/or PRESPLIT hi/lo bf16 planes (hout_hi/lo).
__global__ __launch_bounds__(256) void aggregate(
    const ushort4* __restrict__ hin, const int* __restrict__ row_ptr,
    const int2* __restrict__ csr, const float* __restrict__ dinv,
    const int* __restrict__ perm,
    const float4* __restrict__ bias4, ushort4* __restrict__ hout_bf,
    ushort4* __restrict__ hout_hi, ushort4* __restrict__ hout_lo,
    int n, int do_relu, int scale_out) {
  int g = blockIdx.x * 8 + (threadIdx.x >> 5);
  if (g >= n) return;
  int node = perm[g];
  int t = threadIdx.x & 31;
  int beg = row_ptr[node], end = row_ptr[node + 1];
  ushort4 hs = hin[(size_t)node * 32 + t];   // self-loop (prescaled row)
  float4 acc = make_float4(bf2f(hs.x), bf2f(hs.y), bf2f(hs.z), bf2f(hs.w));
  int p = beg;
  for (; p + 4 <= end; p += 4) {
    int2 e0 = csr[p + 0];
    int2 e1 = csr[p + 1];
    int2 e2 = csr[p + 2];
    int2 e3 = csr[p + 3];
    ushort4 h0 = hin[(size_t)e0.x * 32 + t];
    ushort4 h1 = hin[(size_t)e1.x * 32 + t];
    ushort4 h2 = hin[(size_t)e2.x * 32 + t];
    ushort4 h3 = hin[(size_t)e3.x * 32 + t];
    float w0 = __int_as_float(e0.y), w1 = __int_as_float(e1.y);
    float w2 = __int_as_float(e2.y), w3 = __int_as_float(e3.y);
    acc.x = fmaf(w0, bf2f(h0.x), acc.x); acc.y = fmaf(w0, bf2f(h0.y), acc.y);
    acc.z = fmaf(w0, bf2f(h0.z), acc.z); acc.w = fmaf(w0, bf2f(h0.w), acc.w);
    acc.x = fmaf(w1, bf2f(h1.x), acc.x); acc.y = fmaf(w1, bf2f(h1.y), acc.y);
    acc.z = fmaf(w1, bf2f(h1.z), acc.z); acc.w = fmaf(w1, bf2f(h1.w), acc.w);
    acc.x = fmaf(w2, bf2f(h2.x), acc.x); acc.y = fmaf(w2, bf2f(h2.y), acc.y);
    acc.z = fmaf(w2, bf2f(h2.z), acc.z); acc.w = fmaf(w2, bf2f(h2.w), acc.w);
    acc.x = fmaf(w3, bf2f(h3.x), acc.x); acc.y = fmaf(w3, bf2f(h3.y), acc.y);
    acc.z = fmaf(w3, bf2f(h3.z), acc.z); acc.w = fmaf(w3, bf2f(h3.w), acc.w);
  }
  for (; p < end; ++p) {
    int2 e = csr[p];
    ushort4 hv = hin[(size_t)e.x * 32 + t];
    float wv = __int_as_float(e.y);
    acc.x = fmaf(wv, bf2f(hv.x), acc.x); acc.y = fmaf(wv, bf2f(hv.y), acc.y);
    acc.z = fmaf(wv, bf2f(hv.z), acc.z); acc.w = fmaf(wv, bf2f(hv.w), acc.w);
  }
  float dc = dinv[node];
  float4 val = make_float4(dc * acc.x, dc * acc.y, dc * acc.z, dc * acc.w);
  if (bias4) {
    float4 b = bias4[t];
    val.x += b.x; val.y += b.y; val.z += b.z; val.w += b.w;
  }
  if (do_relu) {
    val.x = fmaxf(val.x, 0.f); val.y = fmaxf(val.y, 0.f);
    val.z = fmaxf(val.z, 0.f); val.w = fmaxf(val.w, 0.f);
  }
  if (scale_out) {
    val.x *= dc; val.y *= dc; val.z *= dc; val.w *= dc;
  }
  size_t o = (size_t)node * 32 + t;
  if (hout_bf) {
    ushort4 ov;
    ov.x = f2bf_rne(val.x); ov.y = f2bf_rne(val.y);
    ov.z = f2bf_rne(val.z); ov.w = f2bf_rne(val.w);
    hout_bf[o] = ov;
  }
  if (hout_hi) {
    ushort4 hv, lv;
    hv.x = f2bf_rne(val.x); lv.x = f2bf_rne(val.x - bf2f(hv.x));
    hv.y = f2bf_rne(val.y); lv.y = f2bf_rne(val.y - bf2f(hv.y));
    hv.z = f2bf_rne(val.z); lv.z = f2bf_rne(val.z - bf2f(hv.z));
    hv.w = f2bf_rne(val.w); lv.w = f2bf_rne(val.w - bf2f(hv.w));
    hout_hi[o] = hv;
    hout_lo[o] = lv;
  }
}

extern "C" void kernel_launch(void* const* d_in, const int* in_sizes, int n_in,
                              void* d_out, int out_size, void* d_ws, size_t ws_size,
                              hipStream_t stream) {
  const float* x   = (const float*)d_in[0];
  const int*   ei  = (const int*)d_in[1];
  const float* ea  = (const float*)d_in[2];
  const float* W1  = (const float*)d_in[3];
  const float* b1  = (const float*)d_in[4];
  const float* Wmu = (const float*)d_in[5];
  const float* bmu = (const float*)d_in[6];
  const float* Wls = (const float*)d_in[7];
  const float* bls = (const float*)d_in[8];
  const int N = in_sizes[0] / 128;
  const int E = in_sizes[2];
  const int* row = ei;
  const int* col = ei + E;

  char* p = (char*)d_ws;
  auto alloc = [&](size_t bytes) -> void* {
    void* r = (void*)p;
    p += (bytes + 255) & ~(size_t)255;
    return r;
  };
  const int nbuck = (N + 255) >> 8;               // 391 coarse buckets (256 nodes)
  const int epb   = (E + NBLK - 1) / NBLK;        // edges per partition block

  float* dinv    = (float*)alloc((size_t)N * 4);
  int*   row_ptr = (int*)alloc((size_t)(N + 1) * 4);
  int*   start   = (int*)alloc(520 * 4);            // nbuck+1 (<=392)
  int*   perm    = (int*)alloc((size_t)nbuck * 256 * 4);
  unsigned short* w1t_hi = (unsigned short*)alloc(128 * 128 * 2);
  unsigned short* w1t_lo = (unsigned short*)alloc(128 * 128 * 2);
  unsigned short* wct_hi = (unsigned short*)alloc(128 * 128 * 2);
  unsigned short* wct_lo = (unsigned short*)alloc(128 * 128 * 2);
  float* bcat    = (float*)alloc(128 * 4);
  int2*  csr     = (int2*)alloc((size_t)E * 8);
  unsigned short* bufAhi = (unsigned short*)alloc((size_t)N * 128 * 2); // agg2 hi
  unsigned short* bufAlo = (unsigned short*)alloc((size_t)N * 128 * 2); // agg2 lo
  unsigned short* bufB = (unsigned short*)alloc((size_t)N * 128 * 2);  // hs1 bf16
  unsigned short* bufC = (unsigned short*)alloc((size_t)N * 128 * 2);  // out1 bf16

  // Aliased scratch (dead before its alias target is first written):
  //  - part (E int2 = 12.8MB) -> bufAhi+bufAlo (first written by agg2, later)
  //  - G / tot                -> bufB (first written by gemm1, after build)
  int2* part = (int2*)bufAhi;
  int*  G    = (int*)bufB;                        // nbuck*NBLK ints = 0.8MB
  int*  tot  = (int*)((char*)bufB + (size_t)nbuck * NBLK * 4);

  float* out_mu = (float*)d_out;
  float* out_ls = out_mu + (size_t)N * 64;

  prep_weights<<<128, 256, 0, stream>>>(W1, Wmu, Wls, bmu, bls,
                                        w1t_hi, w1t_lo, wct_hi, wct_lo, bcat);

  hist_coarse<<<NBLK, 256, 0, stream>>>(col, G, E, nbuck, epb);
  scan_bucket<<<nbuck, NBLK, 0, stream>>>(G, tot);
  scan_start<<<1, 512, 0, stream>>>(tot, start, row_ptr, nbuck, N, E);
  partition_edges<<<NBLK, 256, 0, stream>>>(row, col, ea, G, start, part,
                                            E, nbuck, epb);
  build_fine<<<nbuck, 256, 0, stream>>>(start, part, row_ptr, csr, dinv, perm, N);

  int gblocks = (N + 127) / 128;
  int ablocks = (N + 7) / 8;
  // hs1 = (x @ W1) * dinv[row]  -> bf16 only
  gemm_mfma<<<gblocks, 256, 0, stream>>>(x, nullptr, nullptr, w1t_hi, w1t_lo,
                                         nullptr, dinv, nullptr, nullptr,
                                         bufB, 128, N);
  // out1 = dinv * relu(dinv[c]*(sum w*hs1[r] + hs1[c]) + b1) -> bf16 only
  aggregate<<<ablocks, 256, 0, stream>>>((const ushort4*)bufB, row_ptr, csr, dinv,
                                         perm, (const float4*)b1, (ushort4*)bufC,
                                         nullptr, nullptr, N, 1, 1);
  // agg2 = dinv[c]*(sum w*out1[r] + out1[c])  == A_norm @ h  -> presplit hi/lo
  aggregate<<<ablocks, 256, 0, stream>>>((const ushort4*)bufC, row_ptr, csr, dinv,
                                         perm, nullptr, nullptr, (ushort4*)bufAhi,
                                         (ushort4*)bufAlo, N, 0, 0);
  // [mu | logstd] = agg2 @ [Wmu | Wls] + [bmu | bls]
  gemm_mfma<<<gblocks, 256, 0, stream>>>(nullptr, bufAhi, bufAlo, wct_hi, wct_lo,
                                         bcat, nullptr, out_mu, out_ls,
                                         nullptr, 64, N);
}

// Round 9
// 273.292 us; speedup vs baseline: 1.0712x; 1.0712x over previous
//
#include <hip/hip_runtime.h>
#include <math.h>

// GCN-VGAE encoder, N=100000 nodes, E=1600000 edges, F=H=128, O=64 (fp32 in/out).
// Strategy:
//   - CSR build: two-level ATOMIC-FREE radix partition (global atomics on gfx950
//     write through at 32B/op; plain stores are L2-absorbed). Coarse partition
//     by col>>8 with LDS cursors, then per-bucket fine CSR build in LDS.
//     deg/dinv folded into build_fine via native ds_add_f32 (+lgkmcnt drain —
//     inline-asm DS ops are invisible to compiler waitcnt tracking).
//     build_fine also emits a DEGREE-BALANCED node permutation (per-bucket LDS
//     counting sort by edge count).
//   - Aggregation: warp-gather, 8 nodes x 32 lanes per block, bf16 rows,
//     BATCH-4 edges in flight (batch-8: VGPR 24->36, occ 70->60%, regressed).
//     Wave pairing: the 2 nodes of a 64-lane wave are ADJACENT SORT RANKS
//     (equal degree -> no max-of-2-Poisson wave imbalance), while each block's
//     4 pairs are STRATUM-INTERLEAVED (q = blk + pair*grid) so block durations
//     stay uniform. (Round-8 lesson: consecutive-rank blocks sort block
//     durations by degree -> occupancy 70->50%, regression.)
//     FETCH ~194MB = compulsory 8-XCD re-fetch of the 25.6MB bf16 table.
//     (LDS-tile SpMM experiment rounds 2-4: 20x slower, reverted.)
//   - agg2 epilogue emits PRESPLIT hi/lo bf16 planes; gemm2 A-staging is a
//     pure copy — no fp32 split VALU.
//   - Feature matrices bf16 (halves gather traffic). Symmetric norm factored:
//     pre-scale rows by dinv, aggregate RAW weights, post-scale by dinv[c].
//   - GEMMs on MFMA (16x16x32 bf16) with SPLIT precision: A=Ahi+Alo, W=Whi+Wlo,
//     C = Ahi*Whi + Alo*Whi + Ahi*Wlo  (error ~2^-18, fp32-grade).
//   - conv2/conv3 fused: agg2 = A_norm @ h once, then one GEMM with [Wmu|Wls].

#define NBLK 512    // coarse-partition blocks; each handles ceil(E/NBLK) edges

typedef __attribute__((ext_vector_type(8))) short bf16x8;
typedef __attribute__((ext_vector_type(4))) float f32x4;

__device__ __forceinline__ unsigned short f2bf_rne(float f) {
  unsigned int u = __float_as_uint(f);
  u += 0x7FFFu + ((u >> 16) & 1u);
  return (unsigned short)(u >> 16);
}

__device__ __forceinline__ float bf2f(unsigned short h) {
  return __uint_as_float(((unsigned int)h) << 16);
}

__device__ __forceinline__ unsigned int pack2(unsigned short a, unsigned short b) {
  return (unsigned int)a | ((unsigned int)b << 16);
}

// Native fire-and-forget LDS float atomic add (ds byte address = low 32b of
// the generic pointer).
__device__ __forceinline__ void lds_fadd(float* addr, float v) {
  unsigned int off = (unsigned int)(size_t)addr;
  asm volatile("ds_add_f32 %0, %1" : : "v"(off), "v"(v) : "memory");
}

// Drain ALL outstanding DS ops (incl. inline-asm ones the compiler can't see).
// MUST precede any __syncthreads() that follows lds_fadd use.
__device__ __forceinline__ void ds_drain() {
  asm volatile("s_waitcnt lgkmcnt(0)" ::: "memory");
}

// ---------------- CSR build: two-level atomic-free partition ----------------

// Per-block LDS histogram over coarse buckets (col>>8). G[bucket][blk] layout.
__global__ __launch_bounds__(256) void hist_coarse(const int* __restrict__ col,
                                                   int* __restrict__ G,
                                                   int E, int nbuck, int epb) {
  __shared__ int h[512];
  int blk = blockIdx.x;
  for (int i = threadIdx.x; i < nbuck; i += 256) h[i] = 0;
  __syncthreads();
  int beg = blk * epb;
  int end = min(beg + epb, E);
  for (int p = beg + threadIdx.x; p < end; p += 256)
    atomicAdd(&h[col[p] >> 8], 1);
  __syncthreads();
  for (int i = threadIdx.x; i < nbuck; i += 256)
    G[(size_t)i * NBLK + blk] = h[i];
}

// Per-bucket exclusive scan over the NBLK block-counts; emits bucket totals.
__global__ __launch_bounds__(NBLK) void scan_bucket(int* __restrict__ G,
                                                    int* __restrict__ tot) {
  __shared__ int s[NBLK];
  int b = blockIdx.x;
  int v = G[(size_t)b * NBLK + threadIdx.x];
  s[threadIdx.x] = v;
  __syncthreads();
  for (int off = 1; off < NBLK; off <<= 1) {
    int t = (threadIdx.x >= off) ? s[threadIdx.x - off] : 0;
    __syncthreads();
    s[threadIdx.x] += t;
    __syncthreads();
  }
  G[(size_t)b * NBLK + threadIdx.x] = s[threadIdx.x] - v;   // exclusive
  if (threadIdx.x == NBLK - 1) tot[b] = s[NBLK - 1];
}

// Exclusive scan of bucket totals -> start[0..nbuck] (start[nbuck]=E).
__global__ __launch_bounds__(512) void scan_start(const int* __restrict__ tot,
                                                  int* __restrict__ start,
                                                  int* __restrict__ row_ptr,
                                                  int nbuck, int N, int E) {
  __shared__ int s[512];
  int v = (threadIdx.x < nbuck) ? tot[threadIdx.x] : 0;
  s[threadIdx.x] = v;
  __syncthreads();
  for (int off = 1; off < 512; off <<= 1) {
    int t = (threadIdx.x >= off) ? s[threadIdx.x - off] : 0;
    __syncthreads();
    s[threadIdx.x] += t;
    __syncthreads();
  }
  if (threadIdx.x < nbuck) start[threadIdx.x] = s[threadIdx.x] - v;
  if (threadIdx.x == 511) start[nbuck] = E;
  if (threadIdx.x == 0) row_ptr[N] = E;
}

// Coarse scatter: LDS cursors (start[b] + G[b][blk]); packs row|colLow into .x.
// All writes are plain stores (L2 write-back) — zero global atomics.
__global__ __launch_bounds__(256) void partition_edges(
    const int* __restrict__ row, const int* __restrict__ col,
    const float* __restrict__ w, const int* __restrict__ G,
    const int* __restrict__ start, int2* __restrict__ part,
    int E, int nbuck, int epb) {
  __shared__ int cur[512];
  int blk = blockIdx.x;
  for (int i = threadIdx.x; i < nbuck; i += 256)
    cur[i] = start[i] + G[(size_t)i * NBLK + blk];
  __syncthreads();
  int beg = blk * epb;
  int end = min(beg + epb, E);
  for (int p = beg + threadIdx.x; p < end; p += 256) {
    int c = col[p];
    int pos = atomicAdd(&cur[c >> 8], 1);             // LDS atomic (int, native)
    part[pos] = make_int2(row[p] | ((c & 255) << 17), // row < 2^17
                          __float_as_int(w[p]));
  }
}

// Fine build: one block per bucket (256 nodes). LDS hist + scan -> row_ptr and
// exact CSR slots; accumulates deg (raw weight sum) -> dinv; and emits the
// degree-balanced permutation (per-bucket counting sort by edge count; invalid
// tail nodes key 255 so valid nodes exactly fill perm[0..N)).
__global__ __launch_bounds__(256) void build_fine(const int* __restrict__ start,
                                                  const int2* __restrict__ part,
                                                  int* __restrict__ row_ptr,
                                                  int2* __restrict__ csr,
                                                  float* __restrict__ dinv,
                                                  int* __restrict__ perm,
                                                  int N) {
  __shared__ int hist[256];
  __shared__ int sc[256];
  __shared__ int cur[256];
  __shared__ float deg[256];
  int b = blockIdx.x;
  int ebeg = start[b], eend = start[b + 1];
  hist[threadIdx.x] = 0;
  deg[threadIdx.x] = 0.f;
  __syncthreads();
  for (int p = ebeg + threadIdx.x; p < eend; p += 256) {
    int2 e = part[p];
    int dl = (e.x >> 17) & 255;
    atomicAdd(&hist[dl], 1);
    lds_fadd(&deg[dl], __int_as_float(e.y));
  }
  ds_drain();          // asm ds_add_f32 invisible to compiler waitcnt tracking
  __syncthreads();
  int v = hist[threadIdx.x];
  sc[threadIdx.x] = v;
  __syncthreads();
  for (int off = 1; off < 256; off <<= 1) {
    int t = (threadIdx.x >= off) ? sc[threadIdx.x - off] : 0;
    __syncthreads();
    sc[threadIdx.x] += t;
    __syncthreads();
  }
  int ex = sc[threadIdx.x] - v;   // exclusive
  int node = b * 256 + threadIdx.x;
  if (node < N) {
    row_ptr[node] = ebeg + ex;
    dinv[node] = 1.0f / sqrtf(1.0f + deg[threadIdx.x]);
  }
  cur[threadIdx.x] = ebeg + ex;
  __syncthreads();
  for (int p = ebeg + threadIdx.x; p < eend; p += 256) {
    int2 r = part[p];
    int pos = atomicAdd(&cur[(r.x >> 17) & 255], 1);       // LDS atomic (int)
    csr[pos] = make_int2(r.x & 0x1FFFF, r.y);
  }
  // ---- degree-balanced permutation: counting sort by edge count ----
  __syncthreads();                 // cur/sc/hist reusable now
  int key = (node < N) ? (v > 254 ? 254 : v) : 255;
  sc[threadIdx.x] = 0;
  __syncthreads();
  atomicAdd(&sc[key], 1);          // degree histogram
  __syncthreads();
  int dv = sc[threadIdx.x];
  hist[threadIdx.x] = dv;          // scan buffer
  __syncthreads();
  for (int off = 1; off < 256; off <<= 1) {
    int t = (threadIdx.x >= off) ? hist[threadIdx.x - off] : 0;
    __syncthreads();
    hist[threadIdx.x] += t;
    __syncthreads();
  }
  cur[threadIdx.x] = hist[threadIdx.x] - dv;   // exclusive degree-scan
  __syncthreads();
  int rank = atomicAdd(&cur[key], 1);
  if (node < N) perm[(b << 8) + rank] = node;
}

// Transpose + bf16-split both weight matrices in ONE launch:
//   i < 16384: W1 (128x128)     -> w1t_hi/lo[n][k]
//   else:      [Wmu|Wls] concat -> wct_hi/lo[n][k], + bias concat.
__global__ __launch_bounds__(256) void prep_weights(
    const float* __restrict__ W1,
    const float* __restrict__ Wmu, const float* __restrict__ Wls,
    const float* __restrict__ bmu, const float* __restrict__ bls,
    unsigned short* __restrict__ w1t_hi, unsigned short* __restrict__ w1t_lo,
    unsigned short* __restrict__ wct_hi, unsigned short* __restrict__ wct_lo,
    float* __restrict__ bcat) {
  int i = blockIdx.x * 256 + threadIdx.x;   // 0..32767
  if (i < 16384) {
    int n = i & 127, k = i >> 7;
    float f = W1[(size_t)k * 128 + n];
    unsigned short h = f2bf_rne(f);
    unsigned short l = f2bf_rne(f - bf2f(h));
    w1t_hi[(size_t)n * 128 + k] = h;
    w1t_lo[(size_t)n * 128 + k] = l;
  } else {
    int j = i - 16384;
    int n = j & 127, k = j >> 7;
    float f = (n < 64) ? Wmu[(size_t)k * 64 + n] : Wls[(size_t)k * 64 + (n - 64)];
    unsigned short h = f2bf_rne(f);
    unsigned short l = f2bf_rne(f - bf2f(h));
    wct_hi[(size_t)n * 128 + k] = h;
    wct_lo[(size_t)n * 128 + k] = l;
    if (j < 128) bcat[j] = (j < 64) ? bmu[j] : bls[j - 64];
  }
}

// C[M,128] = (A[M,128] @ W[128,128]) * rowscale[row] + bias, via split-bf16 MFMA.
// A path: either fp32 (split in-kernel) or PRESPLIT bf16 planes AHi/ALo
// (pure-copy staging, no VALU split). WtHi/WtLo are bf16, TRANSPOSED [n][k].
// Block: 256 thr = 4 waves, C-tile 128x128, wave computes 64x64 (4x4 of 16x16).
// LDS XOR-swizzle: slot ^ (row&7).
// Output: fp32 split (C0 cols<split, C1 rest) and/or bf16 mirror Cbf (stride 128).
__global__ __launch_bounds__(256) void gemm_mfma(
    const float* __restrict__ A,
    const unsigned short* __restrict__ AHi, const unsigned short* __restrict__ ALo,
    const unsigned short* __restrict__ WtHi, const unsigned short* __restrict__ WtLo,
    const float* __restrict__ bias, const float* __restrict__ rowscale,
    float* __restrict__ C0, float* __restrict__ C1,
    unsigned short* __restrict__ Cbf, int split, int M) {
  __shared__ uint4 sAhi[1024];   // [row 0..127][slot 0..7] 16B slots, swizzled
  __shared__ uint4 sAlo[1024];
  __shared__ uint4 sWhi[1024];   // [col 0..127][slot 0..7]
  __shared__ uint4 sWlo[1024];

  int tid = threadIdx.x;
  int lane = tid & 63, wid = tid >> 6;
  int wave_r = (wid >> 1) * 64, wave_c = (wid & 1) * 64;
  int lrow = lane & 15, lkb = lane >> 4;   // lkb = k-chunk 0..3
  int rowBase = blockIdx.x * 128;

  f32x4 acc[4][4];
#pragma unroll
  for (int mr = 0; mr < 4; ++mr)
#pragma unroll
    for (int nc = 0; nc < 4; ++nc) acc[mr][nc] = (f32x4){0.f, 0.f, 0.f, 0.f};

  const uint4* WtHi4 = (const uint4*)WtHi;   // row = 16 uint4 (128 bf16)
  const uint4* WtLo4 = (const uint4*)WtLo;
  const uint4* AHi4 = (const uint4*)AHi;
  const uint4* ALo4 = (const uint4*)ALo;

  for (int kt = 0; kt < 128; kt += 64) {
    __syncthreads();
    // stage W tile: 128 cols x 64 k (bf16, already split) -> swizzled LDS
#pragma unroll
    for (int j = 0; j < 4; ++j) {
      int g = tid + 256 * j;            // 0..1023
      int c = g >> 3, k8 = g & 7;
      int slot = k8 ^ (c & 7);
      sWhi[c * 8 + slot] = WtHi4[c * 16 + (kt >> 3) + k8];
      sWlo[c * 8 + slot] = WtLo4[c * 16 + (kt >> 3) + k8];
    }
    // stage A tile: 128 rows x 64 k -> swizzled LDS
    if (AHi) {
      // presplit path: pure copy
#pragma unroll
      for (int j = 0; j < 4; ++j) {
        int g = tid + 256 * j;
        int r = g >> 3, k8 = g & 7;
        int grow = rowBase + r;
        uint4 vh = make_uint4(0u, 0u, 0u, 0u);
        uint4 vl = vh;
        if (grow < M) {
          vh = AHi4[(size_t)grow * 16 + (kt >> 3) + k8];
          vl = ALo4[(size_t)grow * 16 + (kt >> 3) + k8];
        }
        int slot = k8 ^ (r & 7);
        sAhi[r * 8 + slot] = vh;
        sAlo[r * 8 + slot] = vl;
      }
    } else {
      // fp32 path: split hi/lo in-kernel
#pragma unroll
      for (int j = 0; j < 4; ++j) {
        int g = tid + 256 * j;          // 0..1023
        int r = g >> 3, k8 = g & 7;
        int grow = rowBase + r;
        float4 v0 = make_float4(0.f, 0.f, 0.f, 0.f);
        float4 v1 = v0;
        if (grow < M) {
          const float4* Ar = (const float4*)(A + (size_t)grow * 128 + kt);
          v0 = Ar[k8 * 2];
          v1 = Ar[k8 * 2 + 1];
        }
        float f[8] = {v0.x, v0.y, v0.z, v0.w, v1.x, v1.y, v1.z, v1.w};
        unsigned short h[8], l[8];
#pragma unroll
        for (int q = 0; q < 8; ++q) {
          h[q] = f2bf_rne(f[q]);
          l[q] = f2bf_rne(f[q] - bf2f(h[q]));
        }
        int slot = k8 ^ (r & 7);
        sAhi[r * 8 + slot] = make_uint4(pack2(h[0], h[1]), pack2(h[2], h[3]),
                                        pack2(h[4], h[5]), pack2(h[6], h[7]));
        sAlo[r * 8 + slot] = make_uint4(pack2(l[0], l[1]), pack2(l[2], l[3]),
                                        pack2(l[4], l[5]), pack2(l[6], l[7]));
      }
    }
    __syncthreads();
    // compute: 2 MFMA k-steps (K=32 each) per LDS tile
#pragma unroll
    for (int ks = 0; ks < 2; ++ks) {
      bf16x8 ah[4], al[4], bh[4], bl[4];
#pragma unroll
      for (int mr = 0; mr < 4; ++mr) {
        int r = wave_r + mr * 16 + lrow;
        int slot = (ks * 4 + lkb) ^ (r & 7);
        ah[mr] = *(const bf16x8*)&sAhi[r * 8 + slot];
        al[mr] = *(const bf16x8*)&sAlo[r * 8 + slot];
      }
#pragma unroll
      for (int nc = 0; nc < 4; ++nc) {
        int c = wave_c + nc * 16 + lrow;
        int slot = (ks * 4 + lkb) ^ (c & 7);
        bh[nc] = *(const bf16x8*)&sWhi[c * 8 + slot];
        bl[nc] = *(const bf16x8*)&sWlo[c * 8 + slot];
      }
#pragma unroll
      for (int mr = 0; mr < 4; ++mr)
#pragma unroll
        for (int nc = 0; nc < 4; ++nc) {
          acc[mr][nc] = __builtin_amdgcn_mfma_f32_16x16x32_bf16(
              ah[mr], bh[nc], acc[mr][nc], 0, 0, 0);
          acc[mr][nc] = __builtin_amdgcn_mfma_f32_16x16x32_bf16(
              al[mr], bh[nc], acc[mr][nc], 0, 0, 0);
          acc[mr][nc] = __builtin_amdgcn_mfma_f32_16x16x32_bf16(
              ah[mr], bl[nc], acc[mr][nc], 0, 0, 0);
        }
    }
  }

  // epilogue: D[row=(lane>>4)*4+reg][col=lane&15] per 16x16 tile
#pragma unroll
  for (int mr = 0; mr < 4; ++mr) {
    int Rb = rowBase + wave_r + mr * 16 + lkb * 4;
    float sc[4];
#pragma unroll
    for (int reg = 0; reg < 4; ++reg)
      sc[reg] = (rowscale && (Rb + reg) < M) ? rowscale[Rb + reg] : 1.0f;
#pragma unroll
    for (int nc = 0; nc < 4; ++nc) {
      int c = wave_c + nc * 16 + lrow;
      float bb = bias ? bias[c] : 0.f;
      f32x4 v = acc[mr][nc];
#pragma unroll
      for (int reg = 0; reg < 4; ++reg) {
        int R = Rb + reg;
        if (R >= M) continue;
        float val = v[reg] * sc[reg] + bb;
        if (Cbf) Cbf[(size_t)R * 128 + c] = f2bf_rne(val);
        if (C0) {
          if (c < split) C0[(size_t)R * split + c] = val;
          else           C1[(size_t)R * split + (c - split)] = val;
        }
      }
    }
  }
}

// 256 threads = 8 nodes x 32 lanes; each lane owns 4 channels (ushort4 = 8B bf16).
// Batch-4 edges in flight (proven optimum: 24 VGPR, ~70% occupancy).
// Wave pairing: the 2 nodes of a wave are adjacent sort ranks (equal degree);
// each block's 4 pairs are stratum-interleaved (q = blk + pair*grid) so block
// durations stay uniform (round-8 lesson).
// Output: bf16 mirror (hout_bf) and/or PRESPLIT hi/lo bf16 planes (hout_hi/lo).
__global__ __launch_bounds__(256) void aggregate(
    const ushort4* __restrict__ hin, const int* __restrict__ row_ptr,
    const int2* __restrict__ csr, const float* __restrict__ dinv,
    const int* __restrict__ perm,
    const float4* __restrict__ bias4, ushort4* __restrict__ hout_bf,
    ushort4* __restrict__ hout_hi, ushort4* __restrict__ hout_lo,
    int n, int do_relu, int scale_out) {
  int w = threadIdx.x >> 5;                       // node slot 0..7 in block
  int q = blockIdx.x + (w >> 1) * gridDim.x;      // stratum-interleaved pair id
  int g = q * 2 + (w & 1);                        // index into sorted perm
  if (g >= n) return;
  int node = perm[g];
  int t = threadIdx.x & 31;
  int beg = row_ptr[node], end = row_ptr[node + 1];
  ushort4 hs = hin[(size_t)node * 32 + t];   // self-loop (prescaled row)
  float4 acc = make_float4(bf2f(hs.x), bf2f(hs.y), bf2f(hs.z), bf2f(hs.w));
  int p = beg;
  for (; p + 4 <= end; p += 4) {
    int2 e0 = csr[p + 0];
    int2 e1 = csr[p + 1];
    int2 e2 = csr[p + 2];
    int2 e3 = csr[p + 3];
    ushort4 h0 = hin[(size_t)e0.x * 32 + t];
    ushort4 h1 = hin[(size_t)e1.x * 32 + t];
    ushort4 h2 = hin[(size_t)e2.x * 32 + t];
    ushort4 h3 = hin[(size_t)e3.x * 32 + t];
    float w0 = __int_as_float(e0.y), w1 = __int_as_float(e1.y);
    float w2 = __int_as_float(e2.y), w3 = __int_as_float(e3.y);
    acc.x = fmaf(w0, bf2f(h0.x), acc.x); acc.y = fmaf(w0, bf2f(h0.y), acc.y);
    acc.z = fmaf(w0, bf2f(h0.z), acc.z); acc.w = fmaf(w0, bf2f(h0.w), acc.w);
    acc.x = fmaf(w1, bf2f(h1.x), acc.x); acc.y = fmaf(w1, bf2f(h1.y), acc.y);
    acc.z = fmaf(w1, bf2f(h1.z), acc.z); acc.w = fmaf(w1, bf2f(h1.w), acc.w);
    acc.x = fmaf(w2, bf2f(h2.x), acc.x); acc.y = fmaf(w2, bf2f(h2.y), acc.y);
    acc.z = fmaf(w2, bf2f(h2.z), acc.z); acc.w = fmaf(w2, bf2f(h2.w), acc.w);
    acc.x = fmaf(w3, bf2f(h3.x), acc.x); acc.y = fmaf(w3, bf2f(h3.y), acc.y);
    acc.z = fmaf(w3, bf2f(h3.z), acc.z); acc.w = fmaf(w3, bf2f(h3.w), acc.w);
  }
  for (; p < end; ++p) {
    int2 e = csr[p];
    ushort4 hv = hin[(size_t)e.x * 32 + t];
    float wv = __int_as_float(e.y);
    acc.x = fmaf(wv, bf2f(hv.x), acc.x); acc.y = fmaf(wv, bf2f(hv.y), acc.y);
    acc.z = fmaf(wv, bf2f(hv.z), acc.z); acc.w = fmaf(wv, bf2f(hv.w), acc.w);
  }
  float dc = dinv[node];
  float4 val = make_float4(dc * acc.x, dc * acc.y, dc * acc.z, dc * acc.w);
  if (bias4) {
    float4 b = bias4[t];
    val.x += b.x; val.y += b.y; val.z += b.z; val.w += b.w;
  }
  if (do_relu) {
    val.x = fmaxf(val.x, 0.f); val.y = fmaxf(val.y, 0.f);
    val.z = fmaxf(val.z, 0.f); val.w = fmaxf(val.w, 0.f);
  }
  if (scale_out) {
    val.x *= dc; val.y *= dc; val.z *= dc; val.w *= dc;
  }
  size_t o = (size_t)node * 32 + t;
  if (hout_bf) {
    ushort4 ov;
    ov.x = f2bf_rne(val.x); ov.y = f2bf_rne(val.y);
    ov.z = f2bf_rne(val.z); ov.w = f2bf_rne(val.w);
    hout_bf[o] = ov;
  }
  if (hout_hi) {
    ushort4 hv, lv;
    hv.x = f2bf_rne(val.x); lv.x = f2bf_rne(val.x - bf2f(hv.x));
    hv.y = f2bf_rne(val.y); lv.y = f2bf_rne(val.y - bf2f(hv.y));
    hv.z = f2bf_rne(val.z); lv.z = f2bf_rne(val.z - bf2f(hv.z));
    hv.w = f2bf_rne(val.w); lv.w = f2bf_rne(val.w - bf2f(hv.w));
    hout_hi[o] = hv;
    hout_lo[o] = lv;
  }
}

extern "C" void kernel_launch(void* const* d_in, const int* in_sizes, int n_in,
                              void* d_out, int out_size, void* d_ws, size_t ws_size,
                              hipStream_t stream) {
  const float* x   = (const float*)d_in[0];
  const int*   ei  = (const int*)d_in[1];
  const float* ea  = (const float*)d_in[2];
  const float* W1  = (const float*)d_in[3];
  const float* b1  = (const float*)d_in[4];
  const float* Wmu = (const float*)d_in[5];
  const float* bmu = (const float*)d_in[6];
  const float* Wls = (const float*)d_in[7];
  const float* bls = (const float*)d_in[8];
  const int N = in_sizes[0] / 128;
  const int E = in_sizes[2];
  const int* row = ei;
  const int* col = ei + E;

  char* p = (char*)d_ws;
  auto alloc = [&](size_t bytes) -> void* {
    void* r = (void*)p;
    p += (bytes + 255) & ~(size_t)255;
    return r;
  };
  const int nbuck = (N + 255) >> 8;               // 391 coarse buckets (256 nodes)
  const int epb   = (E + NBLK - 1) / NBLK;        // edges per partition block

  float* dinv    = (float*)alloc((size_t)N * 4);
  int*   row_ptr = (int*)alloc((size_t)(N + 1) * 4);
  int*   start   = (int*)alloc(520 * 4);            // nbuck+1 (<=392)
  int*   perm    = (int*)alloc((size_t)nbuck * 256 * 4);
  unsigned short* w1t_hi = (unsigned short*)alloc(128 * 128 * 2);
  unsigned short* w1t_lo = (unsigned short*)alloc(128 * 128 * 2);
  unsigned short* wct_hi = (unsigned short*)alloc(128 * 128 * 2);
  unsigned short* wct_lo = (unsigned short*)alloc(128 * 128 * 2);
  float* bcat    = (float*)alloc(128 * 4);
  int2*  csr     = (int2*)alloc((size_t)E * 8);
  unsigned short* bufAhi = (unsigned short*)alloc((size_t)N * 128 * 2); // agg2 hi
  unsigned short* bufAlo = (unsigned short*)alloc((size_t)N * 128 * 2); // agg2 lo
  unsigned short* bufB = (unsigned short*)alloc((size_t)N * 128 * 2);  // hs1 bf16
  unsigned short* bufC = (unsigned short*)alloc((size_t)N * 128 * 2);  // out1 bf16

  // Aliased scratch (dead before its alias target is first written):
  //  - part (E int2 = 12.8MB) -> bufAhi+bufAlo (first written by agg2, later)
  //  - G / tot                -> bufB (first written by gemm1, after build)
  int2* part = (int2*)bufAhi;
  int*  G    = (int*)bufB;                        // nbuck*NBLK ints = 0.8MB
  int*  tot  = (int*)((char*)bufB + (size_t)nbuck * NBLK * 4);

  float* out_mu = (float*)d_out;
  float* out_ls = out_mu + (size_t)N * 64;

  prep_weights<<<128, 256, 0, stream>>>(W1, Wmu, Wls, bmu, bls,
                                        w1t_hi, w1t_lo, wct_hi, wct_lo, bcat);

  hist_coarse<<<NBLK, 256, 0, stream>>>(col, G, E, nbuck, epb);
  scan_bucket<<<nbuck, NBLK, 0, stream>>>(G, tot);
  scan_start<<<1, 512, 0, stream>>>(tot, start, row_ptr, nbuck, N, E);
  partition_edges<<<NBLK, 256, 0, stream>>>(row, col, ea, G, start, part,
                                            E, nbuck, epb);
  build_fine<<<nbuck, 256, 0, stream>>>(start, part, row_ptr, csr, dinv, perm, N);

  int gblocks = (N + 127) / 128;
  int ablocks = (N + 7) / 8;
  // hs1 = (x @ W1) * dinv[row]  -> bf16 only
  gemm_mfma<<<gblocks, 256, 0, stream>>>(x, nullptr, nullptr, w1t_hi, w1t_lo,
                                         nullptr, dinv, nullptr, nullptr,
                                         bufB, 128, N);
  // out1 = dinv * relu(dinv[c]*(sum w*hs1[r] + hs1[c]) + b1) -> bf16 only
  aggregate<<<ablocks, 256, 0, stream>>>((const ushort4*)bufB, row_ptr, csr, dinv,
                                         perm, (const float4*)b1, (ushort4*)bufC,
                                         nullptr, nullptr, N, 1, 1);
  // agg2 = dinv[c]*(sum w*out1[r] + out1[c])  == A_norm @ h  -> presplit hi/lo
  aggregate<<<ablocks, 256, 0, stream>>>((const ushort4*)bufC, row_ptr, csr, dinv,
                                         perm, nullptr, nullptr, (ushort4*)bufAhi,
                                         (ushort4*)bufAlo, N, 0, 0);
  // [mu | logstd] = agg2 @ [Wmu | Wls] + [bmu | bls]
  gemm_mfma<<<gblocks, 256, 0, stream>>>(nullptr, bufAhi, bufAlo, wct_hi, wct_lo,
                                         bcat, nullptr, out_mu, out_ls,
                                         nullptr, 64, N);
}

// Round 10
// 266.980 us; speedup vs baseline: 1.0965x; 1.0236x over previous
//
#include <hip/hip_runtime.h>
#include <math.h>

// GCN-VGAE encoder, N=100000 nodes, E=1600000 edges, F=H=128, O=64 (fp32 in/out).
// Strategy (consolidated best-known config, round 10):
//   - CSR build: two-level ATOMIC-FREE radix partition (global atomics on gfx950
//     write through at 32B/op; plain stores are L2-absorbed). Coarse partition
//     by col>>8 with LDS cursors, then per-bucket fine CSR build in LDS.
//     deg/dinv folded into build_fine via native ds_add_f32 (+lgkmcnt drain —
//     inline-asm DS ops are invisible to compiler waitcnt tracking).
//     (Degree-balanced perm experiment rounds 8-9: net-negative, removed —
//     aggregate floor is fabric service rate, not wave imbalance.)
//   - Aggregation: warp-gather, 8 nodes x 32 lanes per block, bf16 rows,
//     BATCH-4 edges in flight (batch-8: VGPR 24->36, occ 70->60%, regressed).
//     FETCH ~194MB = compulsory 8-XCD re-fetch of the 25.6MB bf16 table at
//     ~3.7 TB/s random-256B fabric service — structural floor (~68us/pass).
//     (LDS-tile SpMM experiment rounds 2-4: 20x slower, reverted.)
//   - agg2 epilogue emits PRESPLIT hi/lo bf16 planes; gemm2 A-staging is a
//     pure copy — no fp32 split VALU.
//   - Feature matrices bf16 (halves gather traffic). Symmetric norm factored:
//     pre-scale rows by dinv, aggregate RAW weights, post-scale by dinv[c].
//   - GEMMs on MFMA (16x16x32 bf16) with SPLIT precision: A=Ahi+Alo, W=Whi+Wlo,
//     C = Ahi*Whi + Alo*Whi + Ahi*Wlo  (error ~2^-18, fp32-grade).
//   - conv2/conv3 fused: agg2 = A_norm @ h once, then one GEMM with [Wmu|Wls].
//   - prep_weights folded into the hist_coarse launch (128 extra blocks).

#define NBLK 512    // coarse-partition blocks; each handles ceil(E/NBLK) edges

typedef __attribute__((ext_vector_type(8))) short bf16x8;
typedef __attribute__((ext_vector_type(4))) float f32x4;

__device__ __forceinline__ unsigned short f2bf_rne(float f) {
  unsigned int u = __float_as_uint(f);
  u += 0x7FFFu + ((u >> 16) & 1u);
  return (unsigned short)(u >> 16);
}

__device__ __forceinline__ float bf2f(unsigned short h) {
  return __uint_as_float(((unsigned int)h) << 16);
}

__device__ __forceinline__ unsigned int pack2(unsigned short a, unsigned short b) {
  return (unsigned int)a | ((unsigned int)b << 16);
}

// Native fire-and-forget LDS float atomic add (ds byte address = low 32b of
// the generic pointer).
__device__ __forceinline__ void lds_fadd(float* addr, float v) {
  unsigned int off = (unsigned int)(size_t)addr;
  asm volatile("ds_add_f32 %0, %1" : : "v"(off), "v"(v) : "memory");
}

// Drain ALL outstanding DS ops (incl. inline-asm ones the compiler can't see).
// MUST precede any __syncthreads() that follows lds_fadd use.
__device__ __forceinline__ void ds_drain() {
  asm volatile("s_waitcnt lgkmcnt(0)" ::: "memory");
}

// ---------------- CSR build: two-level atomic-free partition ----------------

// Blocks [0,NBLK): per-block LDS histogram over coarse buckets (col>>8),
// G[bucket][blk] layout. Blocks [NBLK,NBLK+128): weight transpose+split prep.
__global__ __launch_bounds__(256) void hist_prep(
    const int* __restrict__ col, int* __restrict__ G,
    int E, int nbuck, int epb,
    const float* __restrict__ W1,
    const float* __restrict__ Wmu, const float* __restrict__ Wls,
    const float* __restrict__ bmu, const float* __restrict__ bls,
    unsigned short* __restrict__ w1t_hi, unsigned short* __restrict__ w1t_lo,
    unsigned short* __restrict__ wct_hi, unsigned short* __restrict__ wct_lo,
    float* __restrict__ bcat) {
  int blk = blockIdx.x;
  if (blk >= NBLK) {
    int i = (blk - NBLK) * 256 + threadIdx.x;   // 0..32767
    if (i < 16384) {
      int n = i & 127, k = i >> 7;
      float f = W1[(size_t)k * 128 + n];
      unsigned short h = f2bf_rne(f);
      unsigned short l = f2bf_rne(f - bf2f(h));
      w1t_hi[(size_t)n * 128 + k] = h;
      w1t_lo[(size_t)n * 128 + k] = l;
    } else {
      int j = i - 16384;
      int n = j & 127, k = j >> 7;
      float f = (n < 64) ? Wmu[(size_t)k * 64 + n]
                         : Wls[(size_t)k * 64 + (n - 64)];
      unsigned short h = f2bf_rne(f);
      unsigned short l = f2bf_rne(f - bf2f(h));
      wct_hi[(size_t)n * 128 + k] = h;
      wct_lo[(size_t)n * 128 + k] = l;
      if (j < 128) bcat[j] = (j < 64) ? bmu[j] : bls[j - 64];
    }
    return;
  }
  __shared__ int h[512];
  for (int i = threadIdx.x; i < nbuck; i += 256) h[i] = 0;
  __syncthreads();
  int beg = blk * epb;
  int end = min(beg + epb, E);
  for (int p = beg + threadIdx.x; p < end; p += 256)
    atomicAdd(&h[col[p] >> 8], 1);
  __syncthreads();
  for (int i = threadIdx.x; i < nbuck; i += 256)
    G[(size_t)i * NBLK + blk] = h[i];
}

// Per-bucket exclusive scan over the NBLK block-counts; emits bucket totals.
__global__ __launch_bounds__(NBLK) void scan_bucket(int* __restrict__ G,
                                                    int* __restrict__ tot) {
  __shared__ int s[NBLK];
  int b = blockIdx.x;
  int v = G[(size_t)b * NBLK + threadIdx.x];
  s[threadIdx.x] = v;
  __syncthreads();
  for (int off = 1; off < NBLK; off <<= 1) {
    int t = (threadIdx.x >= off) ? s[threadIdx.x - off] : 0;
    __syncthreads();
    s[threadIdx.x] += t;
    __syncthreads();
  }
  G[(size_t)b * NBLK + threadIdx.x] = s[threadIdx.x] - v;   // exclusive
  if (threadIdx.x == NBLK - 1) tot[b] = s[NBLK - 1];
}

// Exclusive scan of bucket totals -> start[0..nbuck] (start[nbuck]=E).
__global__ __launch_bounds__(512) void scan_start(const int* __restrict__ tot,
                                                  int* __restrict__ start,
                                                  int* __restrict__ row_ptr,
                                                  int nbuck, int N, int E) {
  __shared__ int s[512];
  int v = (threadIdx.x < nbuck) ? tot[threadIdx.x] : 0;
  s[threadIdx.x] = v;
  __syncthreads();
  for (int off = 1; off < 512; off <<= 1) {
    int t = (threadIdx.x >= off) ? s[threadIdx.x - off] : 0;
    __syncthreads();
    s[threadIdx.x] += t;
    __syncthreads();
  }
  if (threadIdx.x < nbuck) start[threadIdx.x] = s[threadIdx.x] - v;
  if (threadIdx.x == 511) start[nbuck] = E;
  if (threadIdx.x == 0) row_ptr[N] = E;
}

// Coarse scatter: LDS cursors (start[b] + G[b][blk]); packs row|colLow into .x.
// All writes are plain stores (L2 write-back) — zero global atomics.
__global__ __launch_bounds__(256) void partition_edges(
    const int* __restrict__ row, const int* __restrict__ col,
    const float* __restrict__ w, const int* __restrict__ G,
    const int* __restrict__ start, int2* __restrict__ part,
    int E, int nbuck, int epb) {
  __shared__ int cur[512];
  int blk = blockIdx.x;
  for (int i = threadIdx.x; i < nbuck; i += 256)
    cur[i] = start[i] + G[(size_t)i * NBLK + blk];
  __syncthreads();
  int beg = blk * epb;
  int end = min(beg + epb, E);
  for (int p = beg + threadIdx.x; p < end; p += 256) {
    int c = col[p];
    int pos = atomicAdd(&cur[c >> 8], 1);             // LDS atomic (int, native)
    part[pos] = make_int2(row[p] | ((c & 255) << 17), // row < 2^17
                          __float_as_int(w[p]));
  }
}

// Fine build: one block per bucket (256 nodes). LDS hist + scan -> row_ptr and
// exact CSR slots; also accumulates deg (raw weight sum) -> dinv, saving a
// separate csr re-read pass.
__global__ __launch_bounds__(256) void build_fine(const int* __restrict__ start,
                                                  const int2* __restrict__ part,
                                                  int* __restrict__ row_ptr,
                                                  int2* __restrict__ csr,
                                                  float* __restrict__ dinv,
                                                  int N) {
  __shared__ int hist[256];
  __shared__ int sc[256];
  __shared__ int cur[256];
  __shared__ float deg[256];
  int b = blockIdx.x;
  int ebeg = start[b], eend = start[b + 1];
  hist[threadIdx.x] = 0;
  deg[threadIdx.x] = 0.f;
  __syncthreads();
  for (int p = ebeg + threadIdx.x; p < eend; p += 256) {
    int2 e = part[p];
    int dl = (e.x >> 17) & 255;
    atomicAdd(&hist[dl], 1);
    lds_fadd(&deg[dl], __int_as_float(e.y));
  }
  ds_drain();          // asm ds_add_f32 invisible to compiler waitcnt tracking
  __syncthreads();
  int v = hist[threadIdx.x];
  sc[threadIdx.x] = v;
  __syncthreads();
  for (int off = 1; off < 256; off <<= 1) {
    int t = (threadIdx.x >= off) ? sc[threadIdx.x - off] : 0;
    __syncthreads();
    sc[threadIdx.x] += t;
    __syncthreads();
  }
  int ex = sc[threadIdx.x] - v;   // exclusive
  int node = b * 256 + threadIdx.x;
  if (node < N) {
    row_ptr[node] = ebeg + ex;
    dinv[node] = 1.0f / sqrtf(1.0f + deg[threadIdx.x]);
  }
  cur[threadIdx.x] = ebeg + ex;
  __syncthreads();
  for (int p = ebeg + threadIdx.x; p < eend; p += 256) {
    int2 r = part[p];
    int pos = atomicAdd(&cur[(r.x >> 17) & 255], 1);       // LDS atomic (int)
    csr[pos] = make_int2(r.x & 0x1FFFF, r.y);
  }
}

// C[M,128] = (A[M,128] @ W[128,128]) * rowscale[row] + bias, via split-bf16 MFMA.
// A path: either fp32 (split in-kernel) or PRESPLIT bf16 planes AHi/ALo
// (pure-copy staging, no VALU split). WtHi/WtLo are bf16, TRANSPOSED [n][k].
// Block: 256 thr = 4 waves, C-tile 128x128, wave computes 64x64 (4x4 of 16x16).
// LDS XOR-swizzle: slot ^ (row&7).
// Output: fp32 split (C0 cols<split, C1 rest) and/or bf16 mirror Cbf (stride 128).
__global__ __launch_bounds__(256) void gemm_mfma(
    const float* __restrict__ A,
    const unsigned short* __restrict__ AHi, const unsigned short* __restrict__ ALo,
    const unsigned short* __restrict__ WtHi, const unsigned short* __restrict__ WtLo,
    const float* __restrict__ bias, const float* __restrict__ rowscale,
    float* __restrict__ C0, float* __restrict__ C1,
    unsigned short* __restrict__ Cbf, int split, int M) {
  __shared__ uint4 sAhi[1024];   // [row 0..127][slot 0..7] 16B slots, swizzled
  __shared__ uint4 sAlo[1024];
  __shared__ uint4 sWhi[1024];   // [col 0..127][slot 0..7]
  __shared__ uint4 sWlo[1024];

  int tid = threadIdx.x;
  int lane = tid & 63, wid = tid >> 6;
  int wave_r = (wid >> 1) * 64, wave_c = (wid & 1) * 64;
  int lrow = lane & 15, lkb = lane >> 4;   // lkb = k-chunk 0..3
  int rowBase = blockIdx.x * 128;

  f32x4 acc[4][4];
#pragma unroll
  for (int mr = 0; mr < 4; ++mr)
#pragma unroll
    for (int nc = 0; nc < 4; ++nc) acc[mr][nc] = (f32x4){0.f, 0.f, 0.f, 0.f};

  const uint4* WtHi4 = (const uint4*)WtHi;   // row = 16 uint4 (128 bf16)
  const uint4* WtLo4 = (const uint4*)WtLo;
  const uint4* AHi4 = (const uint4*)AHi;
  const uint4* ALo4 = (const uint4*)ALo;

  for (int kt = 0; kt < 128; kt += 64) {
    __syncthreads();
    // stage W tile: 128 cols x 64 k (bf16, already split) -> swizzled LDS
#pragma unroll
    for (int j = 0; j < 4; ++j) {
      int g = tid + 256 * j;            // 0..1023
      int c = g >> 3, k8 = g & 7;
      int slot = k8 ^ (c & 7);
      sWhi[c * 8 + slot] = WtHi4[c * 16 + (kt >> 3) + k8];
      sWlo[c * 8 + slot] = WtLo4[c * 16 + (kt >> 3) + k8];
    }
    // stage A tile: 128 rows x 64 k -> swizzled LDS
    if (AHi) {
      // presplit path: pure copy
#pragma unroll
      for (int j = 0; j < 4; ++j) {
        int g = tid + 256 * j;
        int r = g >> 3, k8 = g & 7;
        int grow = rowBase + r;
        uint4 vh = make_uint4(0u, 0u, 0u, 0u);
        uint4 vl = vh;
        if (grow < M) {
          vh = AHi4[(size_t)grow * 16 + (kt >> 3) + k8];
          vl = ALo4[(size_t)grow * 16 + (kt >> 3) + k8];
        }
        int slot = k8 ^ (r & 7);
        sAhi[r * 8 + slot] = vh;
        sAlo[r * 8 + slot] = vl;
      }
    } else {
      // fp32 path: split hi/lo in-kernel
#pragma unroll
      for (int j = 0; j < 4; ++j) {
        int g = tid + 256 * j;          // 0..1023
        int r = g >> 3, k8 = g & 7;
        int grow = rowBase + r;
        float4 v0 = make_float4(0.f, 0.f, 0.f, 0.f);
        float4 v1 = v0;
        if (grow < M) {
          const float4* Ar = (const float4*)(A + (size_t)grow * 128 + kt);
          v0 = Ar[k8 * 2];
          v1 = Ar[k8 * 2 + 1];
        }
        float f[8] = {v0.x, v0.y, v0.z, v0.w, v1.x, v1.y, v1.z, v1.w};
        unsigned short h[8], l[8];
#pragma unroll
        for (int q = 0; q < 8; ++q) {
          h[q] = f2bf_rne(f[q]);
          l[q] = f2bf_rne(f[q] - bf2f(h[q]));
        }
        int slot = k8 ^ (r & 7);
        sAhi[r * 8 + slot] = make_uint4(pack2(h[0], h[1]), pack2(h[2], h[3]),
                                        pack2(h[4], h[5]), pack2(h[6], h[7]));
        sAlo[r * 8 + slot] = make_uint4(pack2(l[0], l[1]), pack2(l[2], l[3]),
                                        pack2(l[4], l[5]), pack2(l[6], l[7]));
      }
    }
    __syncthreads();
    // compute: 2 MFMA k-steps (K=32 each) per LDS tile
#pragma unroll
    for (int ks = 0; ks < 2; ++ks) {
      bf16x8 ah[4], al[4], bh[4], bl[4];
#pragma unroll
      for (int mr = 0; mr < 4; ++mr) {
        int r = wave_r + mr * 16 + lrow;
        int slot = (ks * 4 + lkb) ^ (r & 7);
        ah[mr] = *(const bf16x8*)&sAhi[r * 8 + slot];
        al[mr] = *(const bf16x8*)&sAlo[r * 8 + slot];
      }
#pragma unroll
      for (int nc = 0; nc < 4; ++nc) {
        int c = wave_c + nc * 16 + lrow;
        int slot = (ks * 4 + lkb) ^ (c & 7);
        bh[nc] = *(const bf16x8*)&sWhi[c * 8 + slot];
        bl[nc] = *(const bf16x8*)&sWlo[c * 8 + slot];
      }
#pragma unroll
      for (int mr = 0; mr < 4; ++mr)
#pragma unroll
        for (int nc = 0; nc < 4; ++nc) {
          acc[mr][nc] = __builtin_amdgcn_mfma_f32_16x16x32_bf16(
              ah[mr], bh[nc], acc[mr][nc], 0, 0, 0);
          acc[mr][nc] = __builtin_amdgcn_mfma_f32_16x16x32_bf16(
              al[mr], bh[nc], acc[mr][nc], 0, 0, 0);
          acc[mr][nc] = __builtin_amdgcn_mfma_f32_16x16x32_bf16(
              ah[mr], bl[nc], acc[mr][nc], 0, 0, 0);
        }
    }
  }

  // epilogue: D[row=(lane>>4)*4+reg][col=lane&15] per 16x16 tile
#pragma unroll
  for (int mr = 0; mr < 4; ++mr) {
    int Rb = rowBase + wave_r + mr * 16 + lkb * 4;
    float sc[4];
#pragma unroll
    for (int reg = 0; reg < 4; ++reg)
      sc[reg] = (rowscale && (Rb + reg) < M) ? rowscale[Rb + reg] : 1.0f;
#pragma unroll
    for (int nc = 0; nc < 4; ++nc) {
      int c = wave_c + nc * 16 + lrow;
      float bb = bias ? bias[c] : 0.f;
      f32x4 v = acc[mr][nc];
#pragma unroll
      for (int reg = 0; reg < 4; ++reg) {
        int R = Rb + reg;
        if (R >= M) continue;
        float val = v[reg] * sc[reg] + bb;
        if (Cbf) Cbf[(size_t)R * 128 + c] = f2bf_rne(val);
        if (C0) {
          if (c < split) C0[(size_t)R * split + c] = val;
          else           C1[(size_t)R * split + (c - split)] = val;
        }
      }
    }
  }
}

// 256 threads = 8 nodes x 32 lanes; each lane owns 4 channels (ushort4 = 8B bf16).
// Batch-4 edges in flight (proven optimum: 24 VGPR, ~70% occupancy).
// Output: bf16 mirror (hout_bf) and/or PRESPLIT hi/lo bf16 planes (hout_hi/lo,
// split computed in-epilogue, hidden under fabric stalls).
__global__ __launch_bounds__(256) void aggregate(
    const ushort4* __restrict__ hin, const int* __restrict__ row_ptr,
    const int2* __restrict__ csr, const float* __restrict__ dinv,
    const float4* __restrict__ bias4, ushort4* __restrict__ hout_bf,
    ushort4* __restrict__ hout_hi, ushort4* __restrict__ hout_lo,
    int n, int do_relu, int scale_out) {
  int node = blockIdx.x * 8 + (threadIdx.x >> 5);
  if (node >= n) return;
  int t = threadIdx.x & 31;
  int beg = row_ptr[node], end = row_ptr[node + 1];
  ushort4 hs = hin[(size_t)node * 32 + t];   // self-loop (prescaled row)
  float4 acc = make_float4(bf2f(hs.x), bf2f(hs.y), bf2f(hs.z), bf2f(hs.w));
  int p = beg;
  for (; p + 4 <= end; p += 4) {
    int2 e0 = csr[p + 0];
    int2 e1 = csr[p + 1];
    int2 e2 = csr[p + 2];
    int2 e3 = csr[p + 3];
    ushort4 h0 = hin[(size_t)e0.x * 32 + t];
    ushort4 h1 = hin[(size_t)e1.x * 32 + t];
    ushort4 h2 = hin[(size_t)e2.x * 32 + t];
    ushort4 h3 = hin[(size_t)e3.x * 32 + t];
    float w0 = __int_as_float(e0.y), w1 = __int_as_float(e1.y);
    float w2 = __int_as_float(e2.y), w3 = __int_as_float(e3.y);
    acc.x = fmaf(w0, bf2f(h0.x), acc.x); acc.y = fmaf(w0, bf2f(h0.y), acc.y);
    acc.z = fmaf(w0, bf2f(h0.z), acc.z); acc.w = fmaf(w0, bf2f(h0.w), acc.w);
    acc.x = fmaf(w1, bf2f(h1.x), acc.x); acc.y = fmaf(w1, bf2f(h1.y), acc.y);
    acc.z = fmaf(w1, bf2f(h1.z), acc.z); acc.w = fmaf(w1, bf2f(h1.w), acc.w);
    acc.x = fmaf(w2, bf2f(h2.x), acc.x); acc.y = fmaf(w2, bf2f(h2.y), acc.y);
    acc.z = fmaf(w2, bf2f(h2.z), acc.z); acc.w = fmaf(w2, bf2f(h2.w), acc.w);
    acc.x = fmaf(w3, bf2f(h3.x), acc.x); acc.y = fmaf(w3, bf2f(h3.y), acc.y);
    acc.z = fmaf(w3, bf2f(h3.z), acc.z); acc.w = fmaf(w3, bf2f(h3.w), acc.w);
  }
  for (; p < end; ++p) {
    int2 e = csr[p];
    ushort4 hv = hin[(size_t)e.x * 32 + t];
    float wv = __int_as_float(e.y);
    acc.x = fmaf(wv, bf2f(hv.x), acc.x); acc.y = fmaf(wv, bf2f(hv.y), acc.y);
    acc.z = fmaf(wv, bf2f(hv.z), acc.z); acc.w = fmaf(wv, bf2f(hv.w), acc.w);
  }
  float dc = dinv[node];
  float4 val = make_float4(dc * acc.x, dc * acc.y, dc * acc.z, dc * acc.w);
  if (bias4) {
    float4 b = bias4[t];
    val.x += b.x; val.y += b.y; val.z += b.z; val.w += b.w;
  }
  if (do_relu) {
    val.x = fmaxf(val.x, 0.f); val.y = fmaxf(val.y, 0.f);
    val.z = fmaxf(val.z, 0.f); val.w = fmaxf(val.w, 0.f);
  }
  if (scale_out) {
    val.x *= dc; val.y *= dc; val.z *= dc; val.w *= dc;
  }
  size_t o = (size_t)node * 32 + t;
  if (hout_bf) {
    ushort4 ov;
    ov.x = f2bf_rne(val.x); ov.y = f2bf_rne(val.y);
    ov.z = f2bf_rne(val.z); ov.w = f2bf_rne(val.w);
    hout_bf[o] = ov;
  }
  if (hout_hi) {
    ushort4 hv, lv;
    hv.x = f2bf_rne(val.x); lv.x = f2bf_rne(val.x - bf2f(hv.x));
    hv.y = f2bf_rne(val.y); lv.y = f2bf_rne(val.y - bf2f(hv.y));
    hv.z = f2bf_rne(val.z); lv.z = f2bf_rne(val.z - bf2f(hv.z));
    hv.w = f2bf_rne(val.w); lv.w = f2bf_rne(val.w - bf2f(hv.w));
    hout_hi[o] = hv;
    hout_lo[o] = lv;
  }
}

extern "C" void kernel_launch(void* const* d_in, const int* in_sizes, int n_in,
                              void* d_out, int out_size, void* d_ws, size_t ws_size,
                              hipStream_t stream) {
  const float* x   = (const float*)d_in[0];
  const int*   ei  = (const int*)d_in[1];
  const float* ea  = (const float*)d_in[2];
  const float* W1  = (const float*)d_in[3];
  const float* b1  = (const float*)d_in[4];
  const float* Wmu = (const float*)d_in[5];
  const float* bmu = (const float*)d_in[6];
  const float* Wls = (const float*)d_in[7];
  const float* bls = (const float*)d_in[8];
  const int N = in_sizes[0] / 128;
  const int E = in_sizes[2];
  const int* row = ei;
  const int* col = ei + E;

  char* p = (char*)d_ws;
  auto alloc = [&](size_t bytes) -> void* {
    void* r = (void*)p;
    p += (bytes + 255) & ~(size_t)255;
    return r;
  };
  const int nbuck = (N + 255) >> 8;               // 391 coarse buckets (256 nodes)
  const int epb   = (E + NBLK - 1) / NBLK;        // edges per partition block

  float* dinv    = (float*)alloc((size_t)N * 4);
  int*   row_ptr = (int*)alloc((size_t)(N + 1) * 4);
  int*   start   = (int*)alloc(520 * 4);            // nbuck+1 (<=392)
  unsigned short* w1t_hi = (unsigned short*)alloc(128 * 128 * 2);
  unsigned short* w1t_lo = (unsigned short*)alloc(128 * 128 * 2);
  unsigned short* wct_hi = (unsigned short*)alloc(128 * 128 * 2);
  unsigned short* wct_lo = (unsigned short*)alloc(128 * 128 * 2);
  float* bcat    = (float*)alloc(128 * 4);
  int2*  csr     = (int2*)alloc((size_t)E * 8);
  unsigned short* bufAhi = (unsigned short*)alloc((size_t)N * 128 * 2); // agg2 hi
  unsigned short* bufAlo = (unsigned short*)alloc((size_t)N * 128 * 2); // agg2 lo
  unsigned short* bufB = (unsigned short*)alloc((size_t)N * 128 * 2);  // hs1 bf16
  unsigned short* bufC = (unsigned short*)alloc((size_t)N * 128 * 2);  // out1 bf16

  // Aliased scratch (dead before its alias target is first written):
  //  - part (E int2 = 12.8MB) -> bufAhi+bufAlo (first written by agg2, later)
  //  - G / tot                -> bufB (first written by gemm1, after build)
  int2* part = (int2*)bufAhi;
  int*  G    = (int*)bufB;                        // nbuck*NBLK ints = 0.8MB
  int*  tot  = (int*)((char*)bufB + (size_t)nbuck * NBLK * 4);

  float* out_mu = (float*)d_out;
  float* out_ls = out_mu + (size_t)N * 64;

  hist_prep<<<NBLK + 128, 256, 0, stream>>>(col, G, E, nbuck, epb,
                                            W1, Wmu, Wls, bmu, bls,
                                            w1t_hi, w1t_lo, wct_hi, wct_lo, bcat);
  scan_bucket<<<nbuck, NBLK, 0, stream>>>(G, tot);
  scan_start<<<1, 512, 0, stream>>>(tot, start, row_ptr, nbuck, N, E);
  partition_edges<<<NBLK, 256, 0, stream>>>(row, col, ea, G, start, part,
                                            E, nbuck, epb);
  build_fine<<<nbuck, 256, 0, stream>>>(start, part, row_ptr, csr, dinv, N);

  int gblocks = (N + 127) / 128;
  int ablocks = (N + 7) / 8;
  // hs1 = (x @ W1) * dinv[row]  -> bf16 only
  gemm_mfma<<<gblocks, 256, 0, stream>>>(x, nullptr, nullptr, w1t_hi, w1t_lo,
                                         nullptr, dinv, nullptr, nullptr,
                                         bufB, 128, N);
  // out1 = dinv * relu(dinv[c]*(sum w*hs1[r] + hs1[c]) + b1) -> bf16 only
  aggregate<<<ablocks, 256, 0, stream>>>((const ushort4*)bufB, row_ptr, csr, dinv,
                                         (const float4*)b1, (ushort4*)bufC,
                                         nullptr, nullptr, N, 1, 1);
  // agg2 = dinv[c]*(sum w*out1[r] + out1[c])  == A_norm @ h  -> presplit hi/lo
  aggregate<<<ablocks, 256, 0, stream>>>((const ushort4*)bufC, row_ptr, csr, dinv,
                                         nullptr, nullptr, (ushort4*)bufAhi,
                                         (ushort4*)bufAlo, N, 0, 0);
  // [mu | logstd] = agg2 @ [Wmu | Wls] + [bmu | bls]
  gemm_mfma<<<gblocks, 256, 0, stream>>>(nullptr, bufAhi, bufAlo, wct_hi, wct_lo,
                                         bcat, nullptr, out_mu, out_ls,
                                         nullptr, 64, N);
}